// Round 5
// baseline (581.487 us; speedup 1.0000x reference)
//
#include <hip/hip_runtime.h>

#define FDIM   128
#define HEADS  4
#define ALPHA  0.2f
#define DMASK  0x03FFFFFF     // low 26 bits = dst
#define PT     4096           // partition tile (edges per block)
#define NBMAX  1568           // max fine buckets supported by static LDS

typedef __attribute__((ext_vector_type(8))) short bf16x8;
typedef __attribute__((ext_vector_type(4))) float f32x4;
typedef __attribute__((ext_vector_type(4))) unsigned u32x4;

// ------- per-node scores + bf16-pack of x (+ fine-bucket histogram slice) ----
// Multi-value butterfly reduction: 10 shuffles/wave instead of 48.
__global__ __launch_bounds__(256) void score_kernel(
    const float* __restrict__ x, const float* __restrict__ W,
    const float* __restrict__ a, float* __restrict__ s_src,
    float* __restrict__ s_dst, unsigned int* __restrict__ xb,
    const int* __restrict__ src, int* __restrict__ hist,
    int E, int HB, int n) {
  __shared__ int h[NBMAX];
  int lane = threadIdx.x & 63;
  int node = (blockIdx.x << 2) + (threadIdx.x >> 6);
  if (node < n) {
    const float2* x2 = (const float2*)x;
    const float2* W2 = (const float2*)W;
    const float2* a2 = (const float2*)a;
    float2 xv = x2[(size_t)node * 64 + lane];

    // bf16 pack (round-to-nearest-even)
    unsigned int u0 = __float_as_uint(xv.x);
    unsigned int u1 = __float_as_uint(xv.y);
    u0 += 0x7fffu + ((u0 >> 16) & 1u);
    u1 += 0x7fffu + ((u1 >> 16) & 1u);
    xb[(size_t)node * 64 + lane] = (u0 >> 16) | (u1 & 0xffff0000u);

    float p[8];   // p[0..3] = rs per head, p[4..7] = rd per head
#pragma unroll
    for (int k = 0; k < HEADS; k++) {
      float2 wv = W2[k * 64 + lane];
      float hx = xv.x * wv.x, hy = xv.y * wv.y;
      float2 as_ = a2[k * 128 + lane];        // a[k, 0:F]
      float2 ad_ = a2[k * 128 + 64 + lane];   // a[k, F:2F]
      p[k]     = hx * as_.x + hy * as_.y;
      p[4 + k] = hx * ad_.x + hy * ad_.y;
    }

    bool h5 = (lane & 32) != 0;
    float q[4];
#pragma unroll
    for (int k = 0; k < 4; k++) {
      float send = h5 ? p[k] : p[4 + k];
      float got = __shfl_xor(send, 32);
      q[k] = (h5 ? p[4 + k] : p[k]) + got;
    }
    bool h4 = (lane & 16) != 0;
    float r[2];
#pragma unroll
    for (int j = 0; j < 2; j++) {
      float send = h4 ? q[j] : q[2 + j];
      float got = __shfl_xor(send, 16);
      r[j] = (h4 ? q[2 + j] : q[j]) + got;
    }
    bool h3 = (lane & 8) != 0;
    float send = h3 ? r[0] : r[1];
    float got = __shfl_xor(send, 8);
    float v = (h3 ? r[1] : r[0]) + got;
    v += __shfl_xor(v, 1);
    v += __shfl_xor(v, 2);
    v += __shfl_xor(v, 4);
    if ((lane & 7) == 0) {
      int s = lane >> 3;
      if (s < 4) s_src[node * HEADS + s] = v;
      else       s_dst[node * HEADS + (s - 4)] = v;
    }
  }

  // histogram slice: blocks [0, HB) each cover 8192 edges with LDS pre-agg
  int b = blockIdx.x;
  if (b < HB) {
    int t = threadIdx.x;
    int NB = (n + 63) >> 6;
    for (int i = t; i < NB; i += 256) h[i] = 0;
    __syncthreads();
    int base = b * 8192;
#pragma unroll 4
    for (int j = 0; j < 32; j++) {
      int i = base + j * 256 + t;
      if (i < E) atomicAdd(&h[src[i] >> 6], 1);
    }
    __syncthreads();
    for (int i = t; i < NB; i += 256)
      if (h[i]) atomicAdd(&hist[i], h[i]);
  }
}

// ---------------- exclusive scan of NB (<=2048) bucket counts: 1 block -------
__global__ __launch_bounds__(256) void scan_kernel(const int* __restrict__ hist,
                                                   int* __restrict__ fine_ptr,
                                                   int* __restrict__ cursor,
                                                   int NB, int E) {
  __shared__ int lds[256];
  int t = threadIdx.x;
  int loc[8];
  int s = 0;
#pragma unroll
  for (int j = 0; j < 8; j++) {
    int idx = t * 8 + j;
    loc[j] = (idx < NB) ? hist[idx] : 0;
    s += loc[j];
  }
  lds[t] = s;
  __syncthreads();
  for (int off = 1; off < 256; off <<= 1) {
    int xv = (t >= off) ? lds[t - off] : 0;
    __syncthreads();
    lds[t] += xv;
    __syncthreads();
  }
  int run = lds[t] - s;
#pragma unroll
  for (int j = 0; j < 8; j++) {
    int idx = t * 8 + j;
    if (idx < NB) {
      fine_ptr[idx] = run;
      cursor[idx]   = run;
    }
    run += loc[j];
  }
  if (t == 0) fine_ptr[NB] = E;
}

// ---------------- partition: tile-sort 4096 edges by fine bucket in LDS ------
__global__ __launch_bounds__(256) void partition_kernel(
    const int* __restrict__ src, const int* __restrict__ dst,
    const float* __restrict__ adj, int* __restrict__ cursor,
    int2* __restrict__ ebuf, int E, int NB) {
  __shared__ int h[NBMAX];
  __shared__ int sc[NBMAX];
  __shared__ int bg[NBMAX];
  __shared__ unsigned short keyarr[PT];
  __shared__ int2 es[PT];
  __shared__ int lds[256];

  int t = threadIdx.x;
  int base = blockIdx.x * PT;
  for (int i = t; i < NB; i += 256) h[i] = 0;
  __syncthreads();

  int ssrc[16];
#pragma unroll
  for (int j = 0; j < 16; j++) {
    int i = base + j * 256 + t;
    ssrc[j] = (i < E) ? src[i] : -1;
    if (ssrc[j] >= 0) atomicAdd(&h[ssrc[j] >> 6], 1);
  }
  __syncthreads();

  int loc[8];
  int s = 0;
#pragma unroll
  for (int j = 0; j < 8; j++) {
    int idx = t * 8 + j;
    loc[j] = (idx < NB) ? h[idx] : 0;
    s += loc[j];
  }
  lds[t] = s;
  __syncthreads();
  for (int off = 1; off < 256; off <<= 1) {
    int xv = (t >= off) ? lds[t - off] : 0;
    __syncthreads();
    lds[t] += xv;
    __syncthreads();
  }
  int run = lds[t] - s;
#pragma unroll
  for (int j = 0; j < 8; j++) {
    int idx = t * 8 + j;
    if (idx < NB) sc[idx] = run;
    run += loc[j];
  }
  __syncthreads();

  for (int i = t; i < NB; i += 256)
    if (h[i]) bg[i] = atomicAdd(&cursor[i], h[i]);
  __syncthreads();

#pragma unroll
  for (int j = 0; j < 16; j++) {
    if (ssrc[j] >= 0) {
      int i = base + j * 256 + t;
      int k = ssrc[j] >> 6;
      int slot = atomicAdd(&sc[k], 1);
      int2 pk;
      pk.x = (int)(((unsigned)(ssrc[j] & 63) << 26) | (unsigned)dst[i]);
      pk.y = __float_as_int(adj[i]);
      es[slot] = pk;
      keyarr[slot] = (unsigned short)k;
    }
  }
  __syncthreads();

  int tc = E - base; if (tc > PT) tc = PT;
  for (int s2 = t; s2 < tc; s2 += 256) {
    int k = keyarr[s2];
    int rank = s2 - (sc[k] - h[k]);
    ebuf[bg[k] + rank] = es[s2];
  }
}

// ---------------- aggregate: MFMA + reg-staged pipelined gathers -------------
// One block per FULL 64-node bucket (preamble passes over ebuf: 8 -> 2).
// 4 waves; wave owns 16 nodes = 4 groups-of-4 (A rows = node_in_group*4+head).
// Gathers are register-staged and software-pipelined ONE WINDOW DEEP: window
// w+1's 32 row loads (+ its s_src/s_dst gathers) issue BEFORE window w's
// compute, so the compiler's counted vmcnt waits only on the older batch and
// the ~600-900cy gather latency hides under ds_write+A-build+ds_read+MFMA.
// rwA/rwB are statically indexed (rule #20); uniform parity branch selects.
// Transpose path: VGPR -> ds_write_b32 (bank (j+lane)%32, 2-way = free) into
// 130-stride xrow -> R4's conflict-free column reads.  Wave-private LDS +
// in-order DS pipe => barrier-free main loop.
__global__ __launch_bounds__(256, 3) void aggregate_kernel(
    const unsigned int* __restrict__ xb, const float* __restrict__ W,
    const float* __restrict__ s_src, const float* __restrict__ s_dst,
    const int* __restrict__ fine_ptr, const int2* __restrict__ ebuf,
    float* __restrict__ out, int n) {
  __shared__ int2  es[2048];
  __shared__ unsigned short xrow[4][32][130];  // [wave][edge][feature+pad]
  __shared__ float evls[4][192];               // [wave][edge*6 + head], +4=own
  __shared__ int   nbeg[65];
  __shared__ int   nrun[64];
  __shared__ int   h[64];

  int t = threadIdx.x, b = blockIdx.x;
  int lane = t & 63, wid = t >> 6;
  int beg = fine_ptr[b];
  int L   = fine_ptr[b + 1] - beg;

  // ---- preamble: count 64 nodes, scan, scatter es (2 passes over ebuf) ----
  if (t < 64) h[t] = 0;
  __syncthreads();
  for (int i = t; i < L; i += 256)
    atomicAdd(&h[(unsigned)ebuf[beg + i].x >> 26], 1);
  __syncthreads();
  if (t < 64) {   // wave-0 shfl inclusive scan of 64 counters
    int v = h[t];
#pragma unroll
    for (int off = 1; off < 64; off <<= 1) {
      int u = __shfl_up(v, off);
      if (lane >= off) v += u;
    }
    nbeg[t + 1] = v;
    nrun[t] = v - h[t];
    if (t == 0) nbeg[0] = 0;
  }
  __syncthreads();
  for (int i = t; i < L; i += 256) {
    int2 pk = ebuf[beg + i];
    int kk = (unsigned)pk.x >> 26;
    int slot = atomicAdd(&nrun[kk], 1);
    es[slot] = pk;
  }
  __syncthreads();

  int el = lane & 31;                  // edge slot in window
  int hp = lane >> 5;                  // head pair for ev compute
  int kb = (lane >> 4) << 3;           // k-base for A/B fragments
  int ha = lane & 3;                   // A-row head
  int na = (lane & 15) >> 2;           // A-row node-in-group
  unsigned dsel = (lane & 1) ? 0x07060302u : 0x05040100u;

  bf16x8 bones;
#pragma unroll
  for (int j = 0; j < 8; j++) bones[j] = (short)0x3F80;  // bf16 1.0

  f32x4 acc[8];
#pragma unroll
  for (int c = 0; c < 8; c++) acc[c] = (f32x4){0.f, 0.f, 0.f, 0.f};
  f32x4 accR = (f32x4){0.f, 0.f, 0.f, 0.f};

  int nb0 = wid * 16;                  // wave's first node-in-bucket

  // issue window (qw,sw): es read + ev gathers + 32 row loads into rw[]
  auto issue_win = [&](int qw, int sw, int2& pko, float2& dvo, float2& svo,
                       unsigned (&rw)[32]) {
    int endq = nbeg[nb0 + qw * 4 + 4];
    int rem = endq - sw;
    int2 pk{0, 0};
    if (el < rem) pk = es[sw + el];
    pko = pk;
    unsigned kk = (unsigned)pk.x >> 26;
    int dv = pk.x & DMASK;
    int ng = (b << 6) + (int)kk;
    svo = *(const float2*)&s_src[ng * 4 + 2 * hp];
    dvo = *(const float2*)&s_dst[dv * 4 + 2 * hp];
#pragma unroll
    for (int j = 0; j < 32; j++) {
      int dd = __builtin_amdgcn_readlane(pk.x, j) & DMASK;
      rw[j] = xb[(((size_t)(unsigned)dd) << 6) + lane];
    }
  };

  // compute window (qw,sw): ev -> evls, ds_write rows, A build, B reads+MFMA
  auto compute_win = [&](int qw, int sw, int2 pk, float2 dvv, float2 sv,
                         unsigned (&rw)[32]) {
    int endq = nbeg[nb0 + qw * 4 + 4];
    int rem = endq - sw;
    unsigned kk = (unsigned)pk.x >> 26;
    int own_e = (int)(kk & 3);
    float adjv = __int_as_float(pk.y);
    float s0 = sv.x + dvv.x; s0 = (s0 >= 0.f) ? s0 : ALPHA * s0;
    float s1 = sv.y + dvv.y; s1 = (s1 >= 0.f) ? s1 : ALPHA * s1;
    float e0 = __expf(s0) * adjv;
    float e1 = __expf(s1) * adjv;
    if (el >= rem) { e0 = 0.f; e1 = 0.f; }   // padded: force exact 0
    *(float2*)&evls[wid][el * 6 + 2 * hp] = float2{e0, e1};
    evls[wid][el * 6 + 4] = __int_as_float(own_e);

    // rows -> LDS (in-order DS pipe; wave-private; WAR with prev reads safe)
#pragma unroll
    for (int j = 0; j < 32; j++)
      *(unsigned*)&xrow[wid][j][2 * lane] = rw[j];

    // A fragments: owner-masked ev, bf16 hi + residual lo
    unsigned hw0, hw1, hw2, hw3, lw0, lw1, lw2, lw3;
#define ABUILD(JP, HW, LW) {                                          \
      int k0 = kb + 2 * (JP), k1 = k0 + 1;                            \
      float m0 = evls[wid][k0 * 6 + ha];                              \
      float m1 = evls[wid][k1 * 6 + ha];                              \
      int o0 = __float_as_int(evls[wid][k0 * 6 + 4]);                 \
      int o1 = __float_as_int(evls[wid][k1 * 6 + 4]);                 \
      m0 = (o0 == na) ? m0 : 0.f;                                     \
      m1 = (o1 == na) ? m1 : 0.f;                                     \
      unsigned u0 = __float_as_uint(m0), u1 = __float_as_uint(m1);    \
      unsigned r0 = u0 + 0x7fffu + ((u0 >> 16) & 1u);                 \
      unsigned r1 = u1 + 0x7fffu + ((u1 >> 16) & 1u);                 \
      HW = __builtin_amdgcn_perm(r1, r0, 0x07060302u);                \
      float l0 = m0 - __uint_as_float(r0 & 0xffff0000u);              \
      float l1 = m1 - __uint_as_float(r1 & 0xffff0000u);              \
      LW = __builtin_amdgcn_perm(__float_as_uint(l1),                 \
                                 __float_as_uint(l0), 0x07060302u); }
    ABUILD(0, hw0, lw0)
    ABUILD(1, hw1, lw1)
    ABUILD(2, hw2, lw2)
    ABUILD(3, hw3, lw3)
#undef ABUILD
    bf16x8 ahi = __builtin_bit_cast(bf16x8, (u32x4){hw0, hw1, hw2, hw3});
    bf16x8 alo = __builtin_bit_cast(bf16x8, (u32x4){lw0, lw1, lw2, lw3});

    int fb = lane & 14;   // even feature within chunk
#pragma unroll
    for (int cc = 0; cc < 8; cc++) {
      unsigned dw[8];
#pragma unroll
      for (int j = 0; j < 8; j++)
        dw[j] = *(const unsigned*)&xrow[wid][kb + j][cc * 16 + fb];
      u32x4 bw = { __builtin_amdgcn_perm(dw[1], dw[0], dsel),
                   __builtin_amdgcn_perm(dw[3], dw[2], dsel),
                   __builtin_amdgcn_perm(dw[5], dw[4], dsel),
                   __builtin_amdgcn_perm(dw[7], dw[6], dsel) };
      bf16x8 bfrag = __builtin_bit_cast(bf16x8, bw);
      acc[cc] = __builtin_amdgcn_mfma_f32_16x16x32_bf16(ahi, bfrag, acc[cc], 0, 0, 0);
      acc[cc] = __builtin_amdgcn_mfma_f32_16x16x32_bf16(alo, bfrag, acc[cc], 0, 0, 0);
    }
    accR = __builtin_amdgcn_mfma_f32_16x16x32_bf16(ahi, bones, accR, 0, 0, 0);
    accR = __builtin_amdgcn_mfma_f32_16x16x32_bf16(alo, bones, accR, 0, 0, 0);
  };

  // epilogue for group q: rowsum rcp, W scale, ELU, mean over heads, store
  auto epilogue = [&](int q) {
    float rinv0 = __builtin_amdgcn_rcpf(accR[0]);
    float rinv1 = __builtin_amdgcn_rcpf(accR[1]);
    float rinv2 = __builtin_amdgcn_rcpf(accR[2]);
    float rinv3 = __builtin_amdgcn_rcpf(accR[3]);
    int ng4 = (b << 6) + nb0 + q * 4 + (lane >> 4);
    bool valid = ng4 < n;
    int fl = lane & 15;
#pragma unroll
    for (int cc = 0; cc < 8; cc++) {
      int f = cc * 16 + fl;
      float o = 0.f;
      float v0 = acc[cc][0] * W[0 * 128 + f] * rinv0;
      o += (v0 > 0.f) ? v0 : (__expf(v0) - 1.f);
      float v1 = acc[cc][1] * W[1 * 128 + f] * rinv1;
      o += (v1 > 0.f) ? v1 : (__expf(v1) - 1.f);
      float v2 = acc[cc][2] * W[2 * 128 + f] * rinv2;
      o += (v2 > 0.f) ? v2 : (__expf(v2) - 1.f);
      float v3 = acc[cc][3] * W[3 * 128 + f] * rinv3;
      o += (v3 > 0.f) ? v3 : (__expf(v3) - 1.f);
      if (valid) out[(size_t)ng4 * 128 + f] = o * 0.25f;
    }
#pragma unroll
    for (int c = 0; c < 8; c++) acc[c] = (f32x4){0.f, 0.f, 0.f, 0.f};
    accR = (f32x4){0.f, 0.f, 0.f, 0.f};
  };

  // ---- pipelined main loop over this wave's windows (4 groups of 4 nodes) --
  int2 pkA, pkB; float2 dvA, dvB, svA, svB;
  unsigned rwA[32], rwB[32];

  int qc = 0, sc = nbeg[nb0];
  while (qc < 4 && sc >= nbeg[nb0 + qc * 4 + 4]) {
    qc++;
    if (qc < 4) sc = nbeg[nb0 + qc * 4];
  }
  if (qc < 4) issue_win(qc, sc, pkA, dvA, svA, rwA);
  bool curA = true;
  while (qc < 4) {
    int qn = qc, sn = sc + 32;
    while (qn < 4 && sn >= nbeg[nb0 + qn * 4 + 4]) {
      qn++;
      if (qn < 4) sn = nbeg[nb0 + qn * 4];
    }
    if (curA) {
      if (qn < 4) issue_win(qn, sn, pkB, dvB, svB, rwB);
      compute_win(qc, sc, pkA, dvA, svA, rwA);
    } else {
      if (qn < 4) issue_win(qn, sn, pkA, dvA, svA, rwA);
      compute_win(qc, sc, pkB, dvB, svB, rwB);
    }
    if (qn != qc) epilogue(qc);
    qc = qn; sc = sn; curA = !curA;
  }
}

extern "C" void kernel_launch(void* const* d_in, const int* in_sizes, int n_in,
                              void* d_out, int out_size, void* d_ws, size_t ws_size,
                              hipStream_t stream) {
  const float* x   = (const float*)d_in[0];
  const int*   edg = (const int*)d_in[1];
  const float* adj = (const float*)d_in[2];
  const float* W   = (const float*)d_in[3];
  const float* a   = (const float*)d_in[4];
  float* out = (float*)d_out;

  int E = in_sizes[2];
  int n = in_sizes[0] / FDIM;
  const int* src = edg;
  const int* dst = edg + E;
  int NB = (n + 63) >> 6;              // fine buckets of 64 nodes (<= NBMAX)
  int HB = (E + 8191) / 8192;          // histogram tiles

  auto align = [](size_t v) { return (v + 255) & ~(size_t)255; };
  char* ws = (char*)d_ws;
  int*   fine_ptr = (int*)ws;          ws += align((size_t)(NB + 1) * 4);
  int*   cursor   = (int*)ws;          ws += align((size_t)NB * 4);
  int*   hist     = (int*)ws;          ws += align((size_t)NB * 4);
  int2*  ebuf     = (int2*)ws;         ws += align((size_t)E * 8);
  float* s_src    = (float*)ws;        ws += align((size_t)n * HEADS * 4);
  float* s_dst    = (float*)ws;        ws += align((size_t)n * HEADS * 4);
  unsigned int* xb = (unsigned int*)ws; ws += align((size_t)n * 64 * 4);

  hipMemsetAsync(hist, 0, (size_t)NB * 4, stream);

  score_kernel<<<(n + 3) / 4, 256, 0, stream>>>(x, W, a, s_src, s_dst, xb,
                                                src, hist, E, HB, n);
  scan_kernel<<<1, 256, 0, stream>>>(hist, fine_ptr, cursor, NB, E);
  partition_kernel<<<(E + PT - 1) / PT, 256, 0, stream>>>(src, dst, adj, cursor,
                                                          ebuf, E, NB);
  aggregate_kernel<<<NB, 256, 0, stream>>>(xb, W, s_src, s_dst, fine_ptr,
                                           ebuf, out, n);
}

// Round 6
// 361.690 us; speedup vs baseline: 1.6077x; 1.6077x over previous
//
#include <hip/hip_runtime.h>

#define FDIM   128
#define HEADS  4
#define ALPHA  0.2f
#define DMASK  0x03FFFFFF     // low 26 bits = dst
#define PT     4096           // partition tile (edges per block)
#define NBMAX  1568           // max fine buckets supported by static LDS

typedef float v2f __attribute__((ext_vector_type(2)));

__device__ __forceinline__ float readlane_f(float v, int lane) {
  return __int_as_float(__builtin_amdgcn_readlane(__float_as_int(v), lane));
}

// ------- per-node scores + bf16-pack of x (+ fine-bucket histogram slice) ----
// Multi-value butterfly reduction: 10 shuffles/wave instead of 48.
__global__ __launch_bounds__(256) void score_kernel(
    const float* __restrict__ x, const float* __restrict__ W,
    const float* __restrict__ a, float* __restrict__ s_src,
    float* __restrict__ s_dst, unsigned int* __restrict__ xb,
    const int* __restrict__ src, int* __restrict__ hist,
    int E, int HB, int n) {
  __shared__ int h[NBMAX];
  int lane = threadIdx.x & 63;
  int node = (blockIdx.x << 2) + (threadIdx.x >> 6);
  if (node < n) {
    const float2* x2 = (const float2*)x;
    const float2* W2 = (const float2*)W;
    const float2* a2 = (const float2*)a;
    float2 xv = x2[(size_t)node * 64 + lane];

    // bf16 pack (round-to-nearest-even)
    unsigned int u0 = __float_as_uint(xv.x);
    unsigned int u1 = __float_as_uint(xv.y);
    u0 += 0x7fffu + ((u0 >> 16) & 1u);
    u1 += 0x7fffu + ((u1 >> 16) & 1u);
    xb[(size_t)node * 64 + lane] = (u0 >> 16) | (u1 & 0xffff0000u);

    float p[8];   // p[0..3] = rs per head, p[4..7] = rd per head
#pragma unroll
    for (int k = 0; k < HEADS; k++) {
      float2 wv = W2[k * 64 + lane];
      float hx = xv.x * wv.x, hy = xv.y * wv.y;
      float2 as_ = a2[k * 128 + lane];        // a[k, 0:F]
      float2 ad_ = a2[k * 128 + 64 + lane];   // a[k, F:2F]
      p[k]     = hx * as_.x + hy * as_.y;
      p[4 + k] = hx * ad_.x + hy * ad_.y;
    }

    bool h5 = (lane & 32) != 0;
    float q[4];
#pragma unroll
    for (int k = 0; k < 4; k++) {
      float send = h5 ? p[k] : p[4 + k];
      float got = __shfl_xor(send, 32);
      q[k] = (h5 ? p[4 + k] : p[k]) + got;
    }
    bool h4 = (lane & 16) != 0;
    float r[2];
#pragma unroll
    for (int j = 0; j < 2; j++) {
      float send = h4 ? q[j] : q[2 + j];
      float got = __shfl_xor(send, 16);
      r[j] = (h4 ? q[2 + j] : q[j]) + got;
    }
    bool h3 = (lane & 8) != 0;
    float send = h3 ? r[0] : r[1];
    float got = __shfl_xor(send, 8);
    float v = (h3 ? r[1] : r[0]) + got;
    v += __shfl_xor(v, 1);
    v += __shfl_xor(v, 2);
    v += __shfl_xor(v, 4);
    if ((lane & 7) == 0) {
      int s = lane >> 3;
      if (s < 4) s_src[node * HEADS + s] = v;
      else       s_dst[node * HEADS + (s - 4)] = v;
    }
  }

  // histogram slice: blocks [0, HB) each cover 8192 edges with LDS pre-agg
  int b = blockIdx.x;
  if (b < HB) {
    int t = threadIdx.x;
    int NB = (n + 63) >> 6;
    for (int i = t; i < NB; i += 256) h[i] = 0;
    __syncthreads();
    int base = b * 8192;
#pragma unroll 4
    for (int j = 0; j < 32; j++) {
      int i = base + j * 256 + t;
      if (i < E) atomicAdd(&h[src[i] >> 6], 1);
    }
    __syncthreads();
    for (int i = t; i < NB; i += 256)
      if (h[i]) atomicAdd(&hist[i], h[i]);
  }
}

// ---------------- exclusive scan of NB (<=2048) bucket counts: 1 block -------
__global__ __launch_bounds__(256) void scan_kernel(const int* __restrict__ hist,
                                                   int* __restrict__ fine_ptr,
                                                   int* __restrict__ cursor,
                                                   int NB, int E) {
  __shared__ int lds[256];
  int t = threadIdx.x;
  int loc[8];
  int s = 0;
#pragma unroll
  for (int j = 0; j < 8; j++) {
    int idx = t * 8 + j;
    loc[j] = (idx < NB) ? hist[idx] : 0;
    s += loc[j];
  }
  lds[t] = s;
  __syncthreads();
  for (int off = 1; off < 256; off <<= 1) {
    int xv = (t >= off) ? lds[t - off] : 0;
    __syncthreads();
    lds[t] += xv;
    __syncthreads();
  }
  int run = lds[t] - s;   // exclusive prefix of this thread's segment
#pragma unroll
  for (int j = 0; j < 8; j++) {
    int idx = t * 8 + j;
    if (idx < NB) {
      fine_ptr[idx] = run;
      cursor[idx]   = run;
    }
    run += loc[j];
  }
  if (t == 0) fine_ptr[NB] = E;
}

// ---------------- partition: tile-sort 4096 edges by fine bucket in LDS ------
__global__ __launch_bounds__(256) void partition_kernel(
    const int* __restrict__ src, const int* __restrict__ dst,
    const float* __restrict__ adj, int* __restrict__ cursor,
    int2* __restrict__ ebuf, int E, int NB) {
  __shared__ int h[NBMAX];
  __shared__ int sc[NBMAX];
  __shared__ int bg[NBMAX];
  __shared__ unsigned short keyarr[PT];
  __shared__ int2 es[PT];
  __shared__ int lds[256];

  int t = threadIdx.x;
  int base = blockIdx.x * PT;
  for (int i = t; i < NB; i += 256) h[i] = 0;
  __syncthreads();

  int ssrc[16];
#pragma unroll
  for (int j = 0; j < 16; j++) {
    int i = base + j * 256 + t;
    ssrc[j] = (i < E) ? src[i] : -1;
    if (ssrc[j] >= 0) atomicAdd(&h[ssrc[j] >> 6], 1);
  }
  __syncthreads();

  int loc[8];
  int s = 0;
#pragma unroll
  for (int j = 0; j < 8; j++) {
    int idx = t * 8 + j;
    loc[j] = (idx < NB) ? h[idx] : 0;
    s += loc[j];
  }
  lds[t] = s;
  __syncthreads();
  for (int off = 1; off < 256; off <<= 1) {
    int xv = (t >= off) ? lds[t - off] : 0;
    __syncthreads();
    lds[t] += xv;
    __syncthreads();
  }
  int run = lds[t] - s;
#pragma unroll
  for (int j = 0; j < 8; j++) {
    int idx = t * 8 + j;
    if (idx < NB) sc[idx] = run;
    run += loc[j];
  }
  __syncthreads();

  for (int i = t; i < NB; i += 256)
    if (h[i]) bg[i] = atomicAdd(&cursor[i], h[i]);
  __syncthreads();

#pragma unroll
  for (int j = 0; j < 16; j++) {
    if (ssrc[j] >= 0) {
      int i = base + j * 256 + t;
      int k = ssrc[j] >> 6;
      int slot = atomicAdd(&sc[k], 1);
      int2 pk;
      pk.x = (int)(((unsigned)(ssrc[j] & 63) << 26) | (unsigned)dst[i]);
      pk.y = __float_as_int(adj[i]);
      es[slot] = pk;
      keyarr[slot] = (unsigned short)k;
    }
  }
  __syncthreads();

  int tc = E - base; if (tc > PT) tc = PT;
  for (int s2 = t; s2 < tc; s2 += 256) {
    int k = keyarr[s2];
    int rank = s2 - (sc[k] - h[k]);
    ebuf[bg[k] + rank] = es[s2];
  }
}

// ---------------- aggregate: quarter-bucket VALU + 1-chunk-deep pipeline -----
// Reverted to the proven R2 structure (93us, VGPR=32): one block per 16-node
// quarter-bucket, 4 waves x 4 nodes, lane = (edge slot 0..15, head 0..3),
// evbuf broadcast via wave-private LDS, v2f fma drain.
// NEW: chunk gathers are double-buffered in NAMED register arrays xwA/xwB
// (flat macros, static indexing only -- R5's lambda-ref arrays spilled to
// scratch: WRITE_SIZE 50->677MB, VGPR=84, 392us).  Chunk c+1's 17 loads
// (s_dst + 16 rows) issue BEFORE chunk c's ev+fma drain, so the counted
// vmcnt keeps them in flight across the drain (~350cy of cover per ~600-900cy
// gather latency), on top of 8 blocks/CU of TLP.
// Padding invariant: slots >= cn carry pk={0,0} -> adj=0 -> ev=0, dst=0
// (row 0 / score 0 loads are cached and harmless).
__global__ __launch_bounds__(256, 8) void aggregate_kernel(
    const unsigned int* __restrict__ xb, const float* __restrict__ W,
    const float* __restrict__ s_src, const float* __restrict__ s_dst,
    const int* __restrict__ fine_ptr, const int2* __restrict__ ebuf,
    float* __restrict__ out, int n) {
  __shared__ int2  es[512];
  __shared__ float evbuf[4][64];
  __shared__ int   nbeg[17];
  __shared__ int   nrun[16];
  __shared__ int   h[16];

  int t = threadIdx.x, bb = blockIdx.x;
  int b0 = bb >> 2, qtr = bb & 3;      // parent 64-bucket, which quarter
  int lane = t & 63, wid = t >> 6;
  int beg = fine_ptr[b0];
  int L   = fine_ptr[b0 + 1] - beg;

  if (t < 16) h[t] = 0;
  __syncthreads();
  for (int i = t; i < L; i += 256) {
    int kk = (unsigned)ebuf[beg + i].x >> 26;
    if ((kk >> 4) == qtr) atomicAdd(&h[kk & 15], 1);
  }
  __syncthreads();
  if (t < 16) {   // lane 0..15 shfl inclusive scan of 16 counters
    int v = h[t];
#pragma unroll
    for (int off = 1; off < 16; off <<= 1) {
      int u = __shfl_up(v, off);
      if (lane >= off) v += u;
    }
    nbeg[t + 1] = v;
    nrun[t] = v - h[t];
    if (t == 0) nbeg[0] = 0;
  }
  __syncthreads();
  for (int i = t; i < L; i += 256) {
    int2 pk = ebuf[beg + i];
    int kk = (unsigned)pk.x >> 26;
    if ((kk >> 4) == qtr) {
      int slot = atomicAdd(&nrun[kk & 15], 1);
      es[slot] = pk;
    }
  }
  __syncthreads();

  int e = lane >> 2;                   // edge slot 0..15
  int k = lane & 3;                    // head

// issue chunk at absolute offset OFF: header + 16 row gathers into PK/SDV/XW
#define LOADHDR(PK, SDV, XW, OFF) do {                                       \
    PK.x = 0; PK.y = 0;                                                      \
    if (e < cnt - (OFF)) PK = es[eb + (OFF) + e];                            \
    SDV = s_dst[(PK.x & DMASK) * HEADS + k];                                 \
    _Pragma("unroll")                                                        \
    for (int j = 0; j < 16; j++) {                                           \
      int dd = __builtin_amdgcn_readlane(PK.x, j * 4) & DMASK;               \
      XW[j] = xb[(((size_t)(unsigned)dd) << 6) + lane];                      \
    }                                                                        \
  } while (0)

// drain chunk: ev phase (waits only its own sdv) then fma drain (its xw)
#define PROCESS(PK, SDV, XW) do {                                            \
    float s_ = ssrc_k + SDV;                                                 \
    s_ = (s_ >= 0.f) ? s_ : ALPHA * s_;                                      \
    float ev_ = __expf(s_) * __int_as_float(PK.y);                           \
    rsum += ev_;                                                             \
    evbuf[wid][lane] = ev_;                                                  \
    _Pragma("unroll")                                                        \
    for (int j = 0; j < 16; j++) {                                           \
      const float4 s4 = *(const float4*)&evbuf[wid][j * 4];                  \
      v2f xv_;                                                               \
      xv_.x = __uint_as_float(XW[j] << 16);                                  \
      xv_.y = __uint_as_float(XW[j] & 0xffff0000u);                          \
      acc0 += s4.x * xv_;                                                    \
      acc1 += s4.y * xv_;                                                    \
      acc2 += s4.z * xv_;                                                    \
      acc3 += s4.w * xv_;                                                    \
    }                                                                        \
  } while (0)

  for (int ni = 0; ni < 4; ni++) {
    int nl = wid * 4 + ni;
    int node = (b0 << 6) + (qtr << 4) + nl;
    if (node >= n) break;              // wave-uniform
    int eb = nbeg[nl], cnt = nbeg[nl + 1] - eb;
    float ssrc_k = s_src[node * HEADS + k];

    v2f acc0{0.f,0.f}, acc1{0.f,0.f}, acc2{0.f,0.f}, acc3{0.f,0.f};
    float rsum = 0.f;

    if (cnt > 0) {
      int2 pkA, pkB;
      float sdvA, sdvB;
      unsigned xwA[16], xwB[16];
      int c = 0;
      LOADHDR(pkA, sdvA, xwA, 0);
      while (true) {
        if (c + 16 < cnt) LOADHDR(pkB, sdvB, xwB, c + 16);
        PROCESS(pkA, sdvA, xwA);
        c += 16;
        if (c >= cnt) break;
        if (c + 16 < cnt) LOADHDR(pkA, sdvA, xwA, c + 16);
        PROCESS(pkB, sdvB, xwB);
        c += 16;
        if (c >= cnt) break;
      }
    }

    // rowsum per head (lane holds head lane&3 after the xor reduce)
    rsum += __shfl_xor(rsum, 4);
    rsum += __shfl_xor(rsum, 8);
    rsum += __shfl_xor(rsum, 16);
    rsum += __shfl_xor(rsum, 32);
    float rinv = __builtin_amdgcn_rcpf(rsum);   // 1 v_rcp vs 8 IEEE divides
    float r0 = readlane_f(rinv, 0), r1 = readlane_f(rinv, 1);
    float r2 = readlane_f(rinv, 2), r3 = readlane_f(rinv, 3);

    const float2* W2 = (const float2*)W;
    float2 o{0.f, 0.f};
    float hx, hy;
    {
      float2 wv = W2[0 * 64 + lane];
      hx = wv.x * acc0.x * r0; hy = wv.y * acc0.y * r0;
      o.x += (hx > 0.f) ? hx : (__expf(hx) - 1.f);
      o.y += (hy > 0.f) ? hy : (__expf(hy) - 1.f);
    }
    {
      float2 wv = W2[1 * 64 + lane];
      hx = wv.x * acc1.x * r1; hy = wv.y * acc1.y * r1;
      o.x += (hx > 0.f) ? hx : (__expf(hx) - 1.f);
      o.y += (hy > 0.f) ? hy : (__expf(hy) - 1.f);
    }
    {
      float2 wv = W2[2 * 64 + lane];
      hx = wv.x * acc2.x * r2; hy = wv.y * acc2.y * r2;
      o.x += (hx > 0.f) ? hx : (__expf(hx) - 1.f);
      o.y += (hy > 0.f) ? hy : (__expf(hy) - 1.f);
    }
    {
      float2 wv = W2[3 * 64 + lane];
      hx = wv.x * acc3.x * r3; hy = wv.y * acc3.y * r3;
      o.x += (hx > 0.f) ? hx : (__expf(hx) - 1.f);
      o.y += (hy > 0.f) ? hy : (__expf(hy) - 1.f);
    }
    o.x *= 0.25f; o.y *= 0.25f;
    ((float2*)out)[(size_t)node * 64 + lane] = o;
  }
#undef LOADHDR
#undef PROCESS
}

extern "C" void kernel_launch(void* const* d_in, const int* in_sizes, int n_in,
                              void* d_out, int out_size, void* d_ws, size_t ws_size,
                              hipStream_t stream) {
  const float* x   = (const float*)d_in[0];
  const int*   edg = (const int*)d_in[1];
  const float* adj = (const float*)d_in[2];
  const float* W   = (const float*)d_in[3];
  const float* a   = (const float*)d_in[4];
  float* out = (float*)d_out;

  int E = in_sizes[2];
  int n = in_sizes[0] / FDIM;
  const int* src = edg;
  const int* dst = edg + E;
  int NB = (n + 63) >> 6;              // fine buckets of 64 nodes (<= NBMAX)
  int HB = (E + 8191) / 8192;          // histogram tiles

  auto align = [](size_t v) { return (v + 255) & ~(size_t)255; };
  char* ws = (char*)d_ws;
  int*   fine_ptr = (int*)ws;          ws += align((size_t)(NB + 1) * 4);
  int*   cursor   = (int*)ws;          ws += align((size_t)NB * 4);
  int*   hist     = (int*)ws;          ws += align((size_t)NB * 4);
  int2*  ebuf     = (int2*)ws;         ws += align((size_t)E * 8);
  float* s_src    = (float*)ws;        ws += align((size_t)n * HEADS * 4);
  float* s_dst    = (float*)ws;        ws += align((size_t)n * HEADS * 4);
  unsigned int* xb = (unsigned int*)ws; ws += align((size_t)n * 64 * 4);

  hipMemsetAsync(hist, 0, (size_t)NB * 4, stream);

  score_kernel<<<(n + 3) / 4, 256, 0, stream>>>(x, W, a, s_src, s_dst, xb,
                                                src, hist, E, HB, n);
  scan_kernel<<<1, 256, 0, stream>>>(hist, fine_ptr, cursor, NB, E);
  partition_kernel<<<(E + PT - 1) / PT, 256, 0, stream>>>(src, dst, adj, cursor,
                                                          ebuf, E, NB);
  aggregate_kernel<<<NB * 4, 256, 0, stream>>>(xb, W, s_src, s_dst, fine_ptr,
                                               ebuf, out, n);
}